// Round 14
// baseline (1319.313 us; speedup 1.0000x reference)
//
#include <hip/hip_runtime.h>
#include <hip/hip_bf16.h>
#include <math.h>

// N=100000, E=1600000, G=64, H=4, C=64, NODE_F=32, DRONE_F=16, OUT=32, L=2

#define NEG_SLOPE 0.2f
#define LN_EPS 1e-5f

struct __align__(8) bf16x4 { __hip_bfloat16 x, y, z, w; };

// h = x@node_W.T + drone_feat[batch]@drone_W.T + (node_b+drone_b)
__global__ __launch_bounds__(256) void k_h0(
        const float* __restrict__ x, const int* __restrict__ batch,
        const float* __restrict__ wnT, const float* __restrict__ wdT,
        const float* __restrict__ bias, const float* __restrict__ drone_feat,
        float* __restrict__ h, int N) {
    __shared__ float xs[16][33];
    __shared__ float ds[16][17];
    int t = threadIdx.x;
    int n0 = blockIdx.x * 16;
    for (int i = t; i < 512; i += 256) {
        int r = i >> 5, c = i & 31;
        int n = n0 + r;
        xs[r][c] = (n < N) ? x[(size_t)n * 32 + c] : 0.f;
    }
    {
        int r = t >> 4, c = t & 15;
        int n = n0 + r;
        int g = (n < N) ? batch[n] : 0;
        ds[r][c] = drone_feat[g * 16 + c];
    }
    __syncthreads();
    int co = t & 63;
    int nsub = t >> 6;
    float b = bias[co];
    float a0 = b, a1 = b, a2 = b, a3 = b;
#pragma unroll
    for (int k = 0; k < 32; ++k) {
        float w = wnT[k * 64 + co];
        a0 = fmaf(xs[nsub * 4 + 0][k], w, a0);
        a1 = fmaf(xs[nsub * 4 + 1][k], w, a1);
        a2 = fmaf(xs[nsub * 4 + 2][k], w, a2);
        a3 = fmaf(xs[nsub * 4 + 3][k], w, a3);
    }
#pragma unroll
    for (int k = 0; k < 16; ++k) {
        float w = wdT[k * 64 + co];
        a0 = fmaf(ds[nsub * 4 + 0][k], w, a0);
        a1 = fmaf(ds[nsub * 4 + 1][k], w, a1);
        a2 = fmaf(ds[nsub * 4 + 2][k], w, a2);
        a3 = fmaf(ds[nsub * 4 + 3][k], w, a3);
    }
    float av[4] = {a0, a1, a2, a3};
#pragma unroll
    for (int j = 0; j < 4; ++j) {
        int n = n0 + nsub * 4 + j;
        if (n < N) h[(size_t)n * 64 + co] = av[j];
    }
}

// degree histogram, 4 edges/thread via int4 coalesced reads
__global__ void k_count(const int* __restrict__ edge_index, int* __restrict__ deg, int E) {
    int i = blockIdx.x * blockDim.x + threadIdx.x;
    int base = i * 4;
    if (base + 3 < E) {
        int4 d = *(const int4*)(edge_index + E + base);
        atomicAdd(deg + d.x, 1);
        atomicAdd(deg + d.y, 1);
        atomicAdd(deg + d.z, 1);
        atomicAdd(deg + d.w, 1);
    } else {
        for (int k = base; k < E; ++k) atomicAdd(deg + edge_index[E + k], 1);
    }
}

// per-1024-chunk sums of (deg+1)
__global__ __launch_bounds__(256) void k_bsum(const int* __restrict__ deg,
                                              int* __restrict__ bsum, int N) {
    int t = threadIdx.x;
    int base = blockIdx.x * 1024 + t * 4;
    int s = 0;
#pragma unroll
    for (int j = 0; j < 4; ++j) s += (base + j < N) ? (deg[base + j] + 1) : 0;
    int lane = t & 63, wid = t >> 6;
#pragma unroll
    for (int off = 32; off >= 1; off >>= 1) s += __shfl_xor(s, off, 64);
    __shared__ int ws[4];
    if (lane == 0) ws[wid] = s;
    __syncthreads();
    if (t == 0) bsum[blockIdx.x] = ws[0] + ws[1] + ws[2] + ws[3];
}

// fill rowptr; write self-loop into csr[rowptr[n]]; init bucket frontiers
// bcur[b] = (#real edges before node 256b) = rowptr[256b] - 256b.
__global__ __launch_bounds__(256) void k_fill(const int* __restrict__ deg,
                                              const int* __restrict__ bsum,
                                              int* __restrict__ rowptr,
                                              int* __restrict__ bcur,
                                              int* __restrict__ csr,
                                              int N, int Etot, int NB) {
    __shared__ int sc[256];
    __shared__ int wsum2[4];
    int t = threadIdx.x;
    int lane = t & 63, wid = t >> 6;
    int bs = (t < NB) ? bsum[t] : 0;
    int v2 = bs;
#pragma unroll
    for (int off = 1; off < 64; off <<= 1) {
        int u = __shfl_up(v2, off, 64);
        if (lane >= off) v2 += u;
    }
    if (lane == 63) wsum2[wid] = v2;
    __syncthreads();
    int woff2 = 0;
    for (int w = 0; w < wid; ++w) woff2 += wsum2[w];
    sc[t] = woff2 + v2 - bs;
    __syncthreads();
    int blkoff = sc[blockIdx.x];

    int base = blockIdx.x * 1024 + t * 4;
    int d[4];
#pragma unroll
    for (int j = 0; j < 4; ++j) d[j] = (base + j < N) ? (deg[base + j] + 1) : 0;
    int s = d[0] + d[1] + d[2] + d[3];
    int v = s;
#pragma unroll
    for (int off = 1; off < 64; off <<= 1) {
        int u = __shfl_up(v, off, 64);
        if (lane >= off) v += u;
    }
    __shared__ int wsum[4];
    if (lane == 63) wsum[wid] = v;
    __syncthreads();
    int woff = 0;
    for (int w = 0; w < wid; ++w) woff += wsum[w];
    int off0 = blkoff + woff + v - s;
#pragma unroll
    for (int j = 0; j < 4; ++j) {
        int idx = base + j;
        if (idx < N) {
            rowptr[idx] = off0;
            csr[off0] = idx;                       // self loop in first slot
            if ((idx & 255) == 0) bcur[idx >> 8] = off0 - idx;   // tmp frontier
        }
        off0 += d[j];
    }
    if (blockIdx.x == 0 && t == 0) rowptr[N] = Etot;
}

// phase B: bin edges (src,dst) into per-bucket dense frontiers of tmp
__global__ void k_bin(const int* __restrict__ edge_index, int* __restrict__ bcur,
                      int2* __restrict__ tmp, int E) {
    int i = blockIdx.x * blockDim.x + threadIdx.x;
    int base = i * 4;
    if (base + 3 < E) {
        int4 sv = *(const int4*)(edge_index + base);
        int4 dv = *(const int4*)(edge_index + E + base);
        tmp[atomicAdd(bcur + (dv.x >> 8), 1)] = make_int2(sv.x, dv.x);
        tmp[atomicAdd(bcur + (dv.y >> 8), 1)] = make_int2(sv.y, dv.y);
        tmp[atomicAdd(bcur + (dv.z >> 8), 1)] = make_int2(sv.z, dv.z);
        tmp[atomicAdd(bcur + (dv.w >> 8), 1)] = make_int2(sv.w, dv.w);
    } else {
        for (int k = base; k < E; ++k)
            tmp[atomicAdd(bcur + (edge_index[E + k] >> 8), 1)] =
                make_int2(edge_index[k], edge_index[E + k]);
    }
}

// phase C: one block per bucket; LDS cursors; csr writes land in a ~17KB window
__global__ __launch_bounds__(256) void k_sort(const int2* __restrict__ tmp,
                                              const int* __restrict__ rowptr,
                                              int* __restrict__ csr, int N) {
    __shared__ int cur[256];
    int b = blockIdx.x;
    int nlo = b * 256;
    int nhi = nlo + 256; if (nhi > N) nhi = N;
    int t = threadIdx.x;
    if (nlo + t < nhi) cur[t] = rowptr[nlo + t] + 1;   // skip self-loop slot
    __syncthreads();
    int tstart = rowptr[nlo] - nlo;
    int tend   = rowptr[nhi] - nhi;
    for (int i = tstart + t; i < tend; i += 256) {
        int2 e = tmp[i];
        int pos = atomicAdd(&cur[e.y - nlo], 1);
        csr[pos] = e.x;
    }
}

// weight transposes + uv + bias, one dispatch
__global__ void k_prep(const float* __restrict__ cW0, const float* __restrict__ cW1,
                       const float* __restrict__ s0, const float* __restrict__ d0,
                       const float* __restrict__ s1, const float* __restrict__ d1,
                       const float* __restrict__ node_W, const float* __restrict__ drone_W,
                       const float* __restrict__ node_b, const float* __restrict__ drone_b,
                       float* __restrict__ wt0, float* __restrict__ wt1,
                       float* __restrict__ uv, float* __restrict__ wnT,
                       float* __restrict__ wdT, float* __restrict__ bias) {
    int i = blockIdx.x * blockDim.x + threadIdx.x;
    if (i < 32768) {
        int j = i & 16383;
        int co = j >> 6, k = j & 63;
        if (i < 16384) wt0[k * 256 + co] = cW0[j];
        else           wt1[k * 256 + co] = cW1[j];
    }
    if (i < 2048) {
        int k = i >> 6, co = i & 63;
        wnT[i] = node_W[co * 32 + k];
    }
    if (i < 1024) {
        int k = i >> 6, co = i & 63;
        wdT[i] = drone_W[co * 16 + k];
        int l = i >> 9, sd = (i >> 8) & 1, head = (i >> 6) & 3, kk = i & 63;
        const float* W   = l ? cW1 : cW0;
        const float* att = l ? (sd ? d1 : s1) : (sd ? d0 : s0);
        float acc = 0.f;
        for (int c = 0; c < 64; ++c)
            acc += W[(head * 64 + c) * 64 + kk] * att[head * 64 + c];
        uv[i] = acc;
    }
    if (i < 64) bias[i] = node_b[i] + drone_b[i];
}

// xh[n][256] = h[n] @ convW.T (bf16) + fused as_/ad_. TN=32 nodes/block.
#define XPAD 68
__global__ __launch_bounds__(256) void k_xh(
        const float* __restrict__ h, const float* __restrict__ wt,
        const float* __restrict__ uv_l, __hip_bfloat16* __restrict__ xh,
        float* __restrict__ as_, float* __restrict__ ad_, int N) {
    __shared__ float hs[32][XPAD];
    int t = threadIdx.x;
    int n0 = blockIdx.x * 32;
    for (int i = t; i < 32 * 64; i += 256) {
        int r = i >> 6, c = i & 63;
        int n = n0 + r;
        hs[r][c] = (n < N) ? h[(size_t)n * 64 + c] : 0.f;
    }
    __syncthreads();
    int co4 = (t & 63) * 4;
    int nsub = t >> 6;
    float4 acc[8];
#pragma unroll
    for (int j = 0; j < 8; ++j) acc[j] = make_float4(0.f, 0.f, 0.f, 0.f);
    const float* wp = wt + co4;
#pragma unroll 2
    for (int k4 = 0; k4 < 16; ++k4) {
        float4 w0 = *(const float4*)(wp + (k4 * 4 + 0) * 256);
        float4 w1 = *(const float4*)(wp + (k4 * 4 + 1) * 256);
        float4 w2 = *(const float4*)(wp + (k4 * 4 + 2) * 256);
        float4 w3 = *(const float4*)(wp + (k4 * 4 + 3) * 256);
#pragma unroll
        for (int j = 0; j < 8; ++j) {
            float4 hv = *(const float4*)&hs[nsub * 8 + j][k4 * 4];
            float4 a = acc[j];
            a.x = fmaf(hv.x, w0.x, fmaf(hv.y, w1.x, fmaf(hv.z, w2.x, fmaf(hv.w, w3.x, a.x))));
            a.y = fmaf(hv.x, w0.y, fmaf(hv.y, w1.y, fmaf(hv.z, w2.y, fmaf(hv.w, w3.y, a.y))));
            a.z = fmaf(hv.x, w0.z, fmaf(hv.y, w1.z, fmaf(hv.z, w2.z, fmaf(hv.w, w3.z, a.z))));
            a.w = fmaf(hv.x, w0.w, fmaf(hv.y, w1.w, fmaf(hv.z, w2.w, fmaf(hv.w, w3.w, a.w))));
            acc[j] = a;
        }
    }
#pragma unroll
    for (int j = 0; j < 8; ++j) {
        int n = n0 + nsub * 8 + j;
        if (n < N) {
            bf16x4 o;
            o.x = __float2bfloat16(acc[j].x);
            o.y = __float2bfloat16(acc[j].y);
            o.z = __float2bfloat16(acc[j].z);
            o.w = __float2bfloat16(acc[j].w);
            *(bf16x4*)(xh + (size_t)n * 256 + co4) = o;
        }
    }
    {
        int row  = t >> 3;
        int head = (t >> 1) & 3;
        int sd   = t & 1;
        int n = n0 + row;
        if (n < N) {
            const float* u = uv_l + sd * 256 + head * 64;
            float a = 0.f;
#pragma unroll
            for (int k4 = 0; k4 < 16; ++k4) {
                float4 hv = *(const float4*)&hs[row][k4 * 4];
                float4 uu = *(const float4*)(u + k4 * 4);
                a += hv.x * uu.x + hv.y * uu.y + hv.z * uu.z + hv.w * uu.w;
            }
            (sd ? ad_ : as_)[n * 4 + head] = a;
        }
    }
}

// One wave per dst node; two edges/iter; lane owns 8 channels (uint4 of bf16).
__global__ __launch_bounds__(256) void k_gat(
        const __hip_bfloat16* __restrict__ xh, const float* __restrict__ as_,
        const float* __restrict__ ad_, const int* __restrict__ rowptr,
        const int* __restrict__ csr, const float* __restrict__ convb,
        const float* __restrict__ ln_g, const float* __restrict__ ln_b,
        float* __restrict__ h, int N) {
    int wid = threadIdx.x >> 6, lane = threadIdx.x & 63;
    int n = blockIdx.x * 4 + wid;
    if (n >= N) return;
    int half = lane >> 5;
    int l32  = lane & 31;
    int head = l32 >> 3;
    int r0 = rowptr[n], r1 = rowptr[n + 1];
    float adv = ad_[(size_t)n * 4 + head];

    float s = 0.f;
    float a0 = 0.f, a1 = 0.f, a2 = 0.f, a3 = 0.f;
    float a4 = 0.f, a5 = 0.f, a6 = 0.f, a7 = 0.f;

    int idx = r0 + half;
    bool v = idx < r1;
    int src = csr[v ? idx : (r1 - 1)];
    float asv = as_[(size_t)src * 4 + head];
    uint4 p = *(const uint4*)(xh + (size_t)src * 256 + l32 * 8);

    for (int i = r0; i < r1; i += 2) {
        bool vc = v; float asc = asv; uint4 pc = p;
        int idxN = i + 2 + half;
        v = idxN < r1;
        if (v) {
            src = csr[idxN];
            asv = as_[(size_t)src * 4 + head];
            p = *(const uint4*)(xh + (size_t)src * 256 + l32 * 8);
        }
        float e = asc + adv;
        e = e > 0.f ? e : NEG_SLOPE * e;
        float w = __expf(e);
        w = vc ? w : 0.f;
        s += w;
        a0 = fmaf(w, __uint_as_float(pc.x << 16),          a0);
        a1 = fmaf(w, __uint_as_float(pc.x & 0xffff0000u),  a1);
        a2 = fmaf(w, __uint_as_float(pc.y << 16),          a2);
        a3 = fmaf(w, __uint_as_float(pc.y & 0xffff0000u),  a3);
        a4 = fmaf(w, __uint_as_float(pc.z << 16),          a4);
        a5 = fmaf(w, __uint_as_float(pc.z & 0xffff0000u),  a5);
        a6 = fmaf(w, __uint_as_float(pc.w << 16),          a6);
        a7 = fmaf(w, __uint_as_float(pc.w & 0xffff0000u),  a7);
    }

    s  += __shfl_xor(s, 32, 64);
    a0 += __shfl_xor(a0, 32, 64); a1 += __shfl_xor(a1, 32, 64);
    a2 += __shfl_xor(a2, 32, 64); a3 += __shfl_xor(a3, 32, 64);
    a4 += __shfl_xor(a4, 32, 64); a5 += __shfl_xor(a5, 32, 64);
    a6 += __shfl_xor(a6, 32, 64); a7 += __shfl_xor(a7, 32, 64);
    float inv = 1.f / (s + 1e-16f);
    a0 *= inv; a1 *= inv; a2 *= inv; a3 *= inv;
    a4 *= inv; a5 *= inv; a6 *= inv; a7 *= inv;
#pragma unroll
    for (int off = 8; off <= 16; off <<= 1) {
        a0 += __shfl_xor(a0, off, 64); a1 += __shfl_xor(a1, off, 64);
        a2 += __shfl_xor(a2, off, 64); a3 += __shfl_xor(a3, off, 64);
        a4 += __shfl_xor(a4, off, 64); a5 += __shfl_xor(a5, off, 64);
        a6 += __shfl_xor(a6, off, 64); a7 += __shfl_xor(a7, off, 64);
    }
    int cbase = (l32 & 7) * 8;
    float4 cbA = *(const float4*)(convb + cbase);
    float4 cbB = *(const float4*)(convb + cbase + 4);
    float o0 = 0.25f * a0 + cbA.x, o1 = 0.25f * a1 + cbA.y;
    float o2 = 0.25f * a2 + cbA.z, o3 = 0.25f * a3 + cbA.w;
    float o4 = 0.25f * a4 + cbB.x, o5 = 0.25f * a5 + cbB.y;
    float o6 = 0.25f * a6 + cbB.z, o7 = 0.25f * a7 + cbB.w;
    float part = o0 + o1 + o2 + o3 + o4 + o5 + o6 + o7;
#pragma unroll
    for (int off = 1; off <= 4; off <<= 1) part += __shfl_xor(part, off, 64);
    float mu = part * (1.f / 64.f);
    float d0 = o0 - mu, d1 = o1 - mu, d2 = o2 - mu, d3 = o3 - mu;
    float d4 = o4 - mu, d5 = o5 - mu, d6 = o6 - mu, d7 = o7 - mu;
    float vs = d0*d0 + d1*d1 + d2*d2 + d3*d3 + d4*d4 + d5*d5 + d6*d6 + d7*d7;
#pragma unroll
    for (int off = 1; off <= 4; off <<= 1) vs += __shfl_xor(vs, off, 64);
    float rstd = rsqrtf(vs * (1.f / 64.f) + LN_EPS);
    float4 gA = *(const float4*)(ln_g + cbase);
    float4 gB = *(const float4*)(ln_g + cbase + 4);
    float4 bA = *(const float4*)(ln_b + cbase);
    float4 bB = *(const float4*)(ln_b + cbase + 4);
    if (lane < 8) {
        float4* hp = (float4*)(h + (size_t)n * 64 + cbase);
        float4 hA = hp[0], hB = hp[1];
        hA.x += fmaxf(d0 * rstd * gA.x + bA.x, 0.f);
        hA.y += fmaxf(d1 * rstd * gA.y + bA.y, 0.f);
        hA.z += fmaxf(d2 * rstd * gA.z + bA.z, 0.f);
        hA.w += fmaxf(d3 * rstd * gA.w + bA.w, 0.f);
        hB.x += fmaxf(d4 * rstd * gB.x + bB.x, 0.f);
        hB.y += fmaxf(d5 * rstd * gB.y + bB.y, 0.f);
        hB.z += fmaxf(d6 * rstd * gB.z + bB.z, 0.f);
        hB.w += fmaxf(d7 * rstd * gB.w + bB.w, 0.f);
        hp[0] = hA; hp[1] = hB;
    }
}

// out = h @ out_W.T + out_b, vectorized
__global__ __launch_bounds__(256) void k_out(
        const float* __restrict__ h, const float* __restrict__ out_W,
        const float* __restrict__ out_b, float* __restrict__ out, int N) {
    __shared__ float hs[8][64];
    int t = threadIdx.x;
    int n0 = blockIdx.x * 8;
    for (int i = t; i < 512; i += 256) {
        int n = n0 + (i >> 6);
        hs[i >> 6][i & 63] = (n < N) ? h[(size_t)n * 64 + (i & 63)] : 0.f;
    }
    __syncthreads();
    int j = t >> 5, o = t & 31;
    int n = n0 + j;
    if (n >= N) return;
    float acc = out_b[o];
    const float4* w4 = (const float4*)(out_W + o * 64);
    const float4* h4 = (const float4*)&hs[j][0];
#pragma unroll
    for (int k = 0; k < 16; ++k) {
        float4 wv = w4[k], hv = h4[k];
        acc += hv.x * wv.x + hv.y * wv.y + hv.z * wv.z + hv.w * wv.w;
    }
    out[(size_t)n * 32 + o] = acc;
}

static inline unsigned cdiv(long long a, long long b) { return (unsigned)((a + b - 1) / b); }

extern "C" void kernel_launch(void* const* d_in, const int* in_sizes, int n_in,
                              void* d_out, int out_size, void* d_ws, size_t ws_size,
                              hipStream_t stream) {
    const float* x          = (const float*)d_in[0];
    const float* drone_feat = (const float*)d_in[1];
    const int*   edge_index = (const int*)d_in[2];
    const int*   batch      = (const int*)d_in[3];
    const float* node_W     = (const float*)d_in[4];
    const float* node_b     = (const float*)d_in[5];
    const float* drone_W    = (const float*)d_in[6];
    const float* drone_b    = (const float*)d_in[7];
    const float* convW[2]   = {(const float*)d_in[8],  (const float*)d_in[14]};
    const float* att_src[2] = {(const float*)d_in[9],  (const float*)d_in[15]};
    const float* att_dst[2] = {(const float*)d_in[10], (const float*)d_in[16]};
    const float* convb[2]   = {(const float*)d_in[11], (const float*)d_in[17]};
    const float* ln_g[2]    = {(const float*)d_in[12], (const float*)d_in[18]};
    const float* ln_b[2]    = {(const float*)d_in[13], (const float*)d_in[19]};
    const float* out_W      = (const float*)d_in[20];
    const float* out_b      = (const float*)d_in[21];
    float* out = (float*)d_out;

    const int N = in_sizes[0] / 32;
    const int E = in_sizes[2] / 2;
    const int Etot = E + N;
    const int NB = cdiv(N, 1024);     // scan blocks
    const int NBK = cdiv(N, 256);     // sort buckets

    char* base = (char*)d_ws;
    size_t off = 0;
    auto alloc = [&](size_t bytes) {
        char* p = base + off;
        off = (off + bytes + 255) & ~(size_t)255;
        return p;
    };
    float*           h      = (float*)alloc((size_t)N * 64 * 4);
    __hip_bfloat16*  xh     = (__hip_bfloat16*)alloc((size_t)N * 256 * 2);
    float*           as_    = (float*)alloc((size_t)N * 4 * 4);
    float*           ad_    = (float*)alloc((size_t)N * 4 * 4);
    float*           wt0    = (float*)alloc((size_t)256 * 64 * 4);
    float*           wt1    = (float*)alloc((size_t)256 * 64 * 4);
    float*           uv     = (float*)alloc((size_t)1024 * 4);
    float*           wnT    = (float*)alloc((size_t)2048 * 4);
    float*           wdT    = (float*)alloc((size_t)1024 * 4);
    float*           bias   = (float*)alloc((size_t)64 * 4);
    int*             deg    = (int*)alloc((size_t)N * 4);
    int*             rowptr = (int*)alloc((size_t)(N + 1) * 4);
    int*             csr    = (int*)alloc((size_t)Etot * 4);
    int2*            tmp    = (int2*)alloc((size_t)E * 8);
    int*             bcur   = (int*)alloc((size_t)NBK * 4);
    int*             bsum   = (int*)alloc((size_t)256 * 4);
    (void)ws_size;
    const float* wt[2] = {wt0, wt1};

    k_prep<<<128, 256, 0, stream>>>(convW[0], convW[1], att_src[0], att_dst[0],
                                    att_src[1], att_dst[1], node_W, drone_W,
                                    node_b, drone_b, wt0, wt1, uv, wnT, wdT, bias);

    k_h0<<<cdiv(N, 16), 256, 0, stream>>>(x, batch, wnT, wdT, bias, drone_feat, h, N);

    (void)hipMemsetAsync(deg, 0, (size_t)N * 4, stream);
    k_count<<<cdiv(cdiv(E, 4), 256), 256, 0, stream>>>(edge_index, deg, E);
    k_bsum<<<NB, 256, 0, stream>>>(deg, bsum, N);
    k_fill<<<NB, 256, 0, stream>>>(deg, bsum, rowptr, bcur, csr, N, Etot, NB);
    k_bin<<<cdiv(cdiv(E, 4), 256), 256, 0, stream>>>(edge_index, bcur, tmp, E);
    k_sort<<<NBK, 256, 0, stream>>>(tmp, rowptr, csr, N);

    for (int l = 0; l < 2; ++l) {
        k_xh<<<cdiv(N, 32), 256, 0, stream>>>(h, wt[l], uv + l * 512, xh, as_, ad_, N);
        k_gat<<<cdiv(N, 4), 256, 0, stream>>>(xh, as_, ad_, rowptr, csr, convb[l],
                                              ln_g[l], ln_b[l], h, N);
    }

    k_out<<<cdiv(N, 8), 256, 0, stream>>>(h, out_W, out_b, out, N);
}

// Round 15
// 867.046 us; speedup vs baseline: 1.5216x; 1.5216x over previous
//
#include <hip/hip_runtime.h>
#include <hip/hip_bf16.h>
#include <math.h>

// N=100000, E=1600000, G=64, H=4, C=64, NODE_F=32, DRONE_F=16, OUT=32, L=2

#define NEG_SLOPE 0.2f
#define LN_EPS 1e-5f

struct __align__(8) bf16x4 { __hip_bfloat16 x, y, z, w; };

// h = x@node_W.T + drone_feat[batch]@drone_W.T + (node_b+drone_b)
__global__ __launch_bounds__(256) void k_h0(
        const float* __restrict__ x, const int* __restrict__ batch,
        const float* __restrict__ wnT, const float* __restrict__ wdT,
        const float* __restrict__ bias, const float* __restrict__ drone_feat,
        float* __restrict__ h, int N) {
    __shared__ float xs[16][33];
    __shared__ float ds[16][17];
    int t = threadIdx.x;
    int n0 = blockIdx.x * 16;
    for (int i = t; i < 512; i += 256) {
        int r = i >> 5, c = i & 31;
        int n = n0 + r;
        xs[r][c] = (n < N) ? x[(size_t)n * 32 + c] : 0.f;
    }
    {
        int r = t >> 4, c = t & 15;
        int n = n0 + r;
        int g = (n < N) ? batch[n] : 0;
        ds[r][c] = drone_feat[g * 16 + c];
    }
    __syncthreads();
    int co = t & 63;
    int nsub = t >> 6;
    float b = bias[co];
    float a0 = b, a1 = b, a2 = b, a3 = b;
#pragma unroll
    for (int k = 0; k < 32; ++k) {
        float w = wnT[k * 64 + co];
        a0 = fmaf(xs[nsub * 4 + 0][k], w, a0);
        a1 = fmaf(xs[nsub * 4 + 1][k], w, a1);
        a2 = fmaf(xs[nsub * 4 + 2][k], w, a2);
        a3 = fmaf(xs[nsub * 4 + 3][k], w, a3);
    }
#pragma unroll
    for (int k = 0; k < 16; ++k) {
        float w = wdT[k * 64 + co];
        a0 = fmaf(ds[nsub * 4 + 0][k], w, a0);
        a1 = fmaf(ds[nsub * 4 + 1][k], w, a1);
        a2 = fmaf(ds[nsub * 4 + 2][k], w, a2);
        a3 = fmaf(ds[nsub * 4 + 3][k], w, a3);
    }
    float av[4] = {a0, a1, a2, a3};
#pragma unroll
    for (int j = 0; j < 4; ++j) {
        int n = n0 + nsub * 4 + j;
        if (n < N) h[(size_t)n * 64 + co] = av[j];
    }
}

// degree histogram, 1 edge/thread (max parallelism, distributed atomics)
__global__ void k_count(const int* __restrict__ edge_index, int* __restrict__ deg, int E) {
    int i = blockIdx.x * blockDim.x + threadIdx.x;
    if (i < E) atomicAdd(deg + edge_index[E + i], 1);
}

// per-1024-chunk sums of (deg+1)
__global__ __launch_bounds__(256) void k_bsum(const int* __restrict__ deg,
                                              int* __restrict__ bsum, int N) {
    int t = threadIdx.x;
    int base = blockIdx.x * 1024 + t * 4;
    int s = 0;
#pragma unroll
    for (int j = 0; j < 4; ++j) s += (base + j < N) ? (deg[base + j] + 1) : 0;
    int lane = t & 63, wid = t >> 6;
#pragma unroll
    for (int off = 32; off >= 1; off >>= 1) s += __shfl_xor(s, off, 64);
    __shared__ int ws[4];
    if (lane == 0) ws[wid] = s;
    __syncthreads();
    if (t == 0) bsum[blockIdx.x] = ws[0] + ws[1] + ws[2] + ws[3];
}

// fill rowptr/cursor; each block re-scans bsum (NB<=256) for its offset.
// Self-loop written into csr[rowptr[n]] (monotone dense writes); cursor starts
// at rowptr+1 — removes N random atomics from k_scatter.
__global__ __launch_bounds__(256) void k_fill(const int* __restrict__ deg,
                                              const int* __restrict__ bsum,
                                              int* __restrict__ rowptr,
                                              int* __restrict__ cursor,
                                              int* __restrict__ csr,
                                              int N, int Etot, int NB) {
    __shared__ int sc[256];
    __shared__ int wsum2[4];
    int t = threadIdx.x;
    int lane = t & 63, wid = t >> 6;
    int bs = (t < NB) ? bsum[t] : 0;
    int v2 = bs;
#pragma unroll
    for (int off = 1; off < 64; off <<= 1) {
        int u = __shfl_up(v2, off, 64);
        if (lane >= off) v2 += u;
    }
    if (lane == 63) wsum2[wid] = v2;
    __syncthreads();
    int woff2 = 0;
    for (int w = 0; w < wid; ++w) woff2 += wsum2[w];
    sc[t] = woff2 + v2 - bs;
    __syncthreads();
    int blkoff = sc[blockIdx.x];

    int base = blockIdx.x * 1024 + t * 4;
    int d[4];
#pragma unroll
    for (int j = 0; j < 4; ++j) d[j] = (base + j < N) ? (deg[base + j] + 1) : 0;
    int s = d[0] + d[1] + d[2] + d[3];
    int v = s;
#pragma unroll
    for (int off = 1; off < 64; off <<= 1) {
        int u = __shfl_up(v, off, 64);
        if (lane >= off) v += u;
    }
    __shared__ int wsum[4];
    if (lane == 63) wsum[wid] = v;
    __syncthreads();
    int woff = 0;
    for (int w = 0; w < wid; ++w) woff += wsum[w];
    int off0 = blkoff + woff + v - s;
#pragma unroll
    for (int j = 0; j < 4; ++j) {
        int idx = base + j;
        if (idx < N) {
            rowptr[idx] = off0;
            csr[off0] = idx;          // self loop occupies the first slot
            cursor[idx] = off0 + 1;
        }
        off0 += d[j];
    }
    if (blockIdx.x == 0 && t == 0) rowptr[N] = Etot;
}

// scatter real edges, 1 edge/thread (distributed atomics)
__global__ void k_scatter(const int* __restrict__ edge_index, int* __restrict__ cursor,
                          int* __restrict__ csr, int E) {
    int i = blockIdx.x * blockDim.x + threadIdx.x;
    if (i >= E) return;
    int s = edge_index[i];
    int d = edge_index[E + i];
    int pos = atomicAdd(cursor + d, 1);
    csr[pos] = s;
}

// weight transposes + uv + bias, one dispatch
__global__ void k_prep(const float* __restrict__ cW0, const float* __restrict__ cW1,
                       const float* __restrict__ s0, const float* __restrict__ d0,
                       const float* __restrict__ s1, const float* __restrict__ d1,
                       const float* __restrict__ node_W, const float* __restrict__ drone_W,
                       const float* __restrict__ node_b, const float* __restrict__ drone_b,
                       float* __restrict__ wt0, float* __restrict__ wt1,
                       float* __restrict__ uv, float* __restrict__ wnT,
                       float* __restrict__ wdT, float* __restrict__ bias) {
    int i = blockIdx.x * blockDim.x + threadIdx.x;
    if (i < 32768) {
        int j = i & 16383;
        int co = j >> 6, k = j & 63;
        if (i < 16384) wt0[k * 256 + co] = cW0[j];
        else           wt1[k * 256 + co] = cW1[j];
    }
    if (i < 2048) {
        int k = i >> 6, co = i & 63;
        wnT[i] = node_W[co * 32 + k];
    }
    if (i < 1024) {
        int k = i >> 6, co = i & 63;
        wdT[i] = drone_W[co * 16 + k];
        int l = i >> 9, sd = (i >> 8) & 1, head = (i >> 6) & 3, kk = i & 63;
        const float* W   = l ? cW1 : cW0;
        const float* att = l ? (sd ? d1 : s1) : (sd ? d0 : s0);
        float acc = 0.f;
        for (int c = 0; c < 64; ++c)
            acc += W[(head * 64 + c) * 64 + kk] * att[head * 64 + c];
        uv[i] = acc;
    }
    if (i < 64) bias[i] = node_b[i] + drone_b[i];
}

// xh[n][256] = h[n] @ convW.T (bf16) + fused as_/ad_. TN=32 nodes/block.
#define XPAD 68
__global__ __launch_bounds__(256) void k_xh(
        const float* __restrict__ h, const float* __restrict__ wt,
        const float* __restrict__ uv_l, __hip_bfloat16* __restrict__ xh,
        float* __restrict__ as_, float* __restrict__ ad_, int N) {
    __shared__ float hs[32][XPAD];
    int t = threadIdx.x;
    int n0 = blockIdx.x * 32;
    for (int i = t; i < 32 * 64; i += 256) {
        int r = i >> 6, c = i & 63;
        int n = n0 + r;
        hs[r][c] = (n < N) ? h[(size_t)n * 64 + c] : 0.f;
    }
    __syncthreads();
    int co4 = (t & 63) * 4;
    int nsub = t >> 6;
    float4 acc[8];
#pragma unroll
    for (int j = 0; j < 8; ++j) acc[j] = make_float4(0.f, 0.f, 0.f, 0.f);
    const float* wp = wt + co4;
#pragma unroll 2
    for (int k4 = 0; k4 < 16; ++k4) {
        float4 w0 = *(const float4*)(wp + (k4 * 4 + 0) * 256);
        float4 w1 = *(const float4*)(wp + (k4 * 4 + 1) * 256);
        float4 w2 = *(const float4*)(wp + (k4 * 4 + 2) * 256);
        float4 w3 = *(const float4*)(wp + (k4 * 4 + 3) * 256);
#pragma unroll
        for (int j = 0; j < 8; ++j) {
            float4 hv = *(const float4*)&hs[nsub * 8 + j][k4 * 4];
            float4 a = acc[j];
            a.x = fmaf(hv.x, w0.x, fmaf(hv.y, w1.x, fmaf(hv.z, w2.x, fmaf(hv.w, w3.x, a.x))));
            a.y = fmaf(hv.x, w0.y, fmaf(hv.y, w1.y, fmaf(hv.z, w2.y, fmaf(hv.w, w3.y, a.y))));
            a.z = fmaf(hv.x, w0.z, fmaf(hv.y, w1.z, fmaf(hv.z, w2.z, fmaf(hv.w, w3.z, a.z))));
            a.w = fmaf(hv.x, w0.w, fmaf(hv.y, w1.w, fmaf(hv.z, w2.w, fmaf(hv.w, w3.w, a.w))));
            acc[j] = a;
        }
    }
#pragma unroll
    for (int j = 0; j < 8; ++j) {
        int n = n0 + nsub * 8 + j;
        if (n < N) {
            bf16x4 o;
            o.x = __float2bfloat16(acc[j].x);
            o.y = __float2bfloat16(acc[j].y);
            o.z = __float2bfloat16(acc[j].z);
            o.w = __float2bfloat16(acc[j].w);
            *(bf16x4*)(xh + (size_t)n * 256 + co4) = o;
        }
    }
    {
        int row  = t >> 3;
        int head = (t >> 1) & 3;
        int sd   = t & 1;
        int n = n0 + row;
        if (n < N) {
            const float* u = uv_l + sd * 256 + head * 64;
            float a = 0.f;
#pragma unroll
            for (int k4 = 0; k4 < 16; ++k4) {
                float4 hv = *(const float4*)&hs[row][k4 * 4];
                float4 uu = *(const float4*)(u + k4 * 4);
                a += hv.x * uu.x + hv.y * uu.y + hv.z * uu.z + hv.w * uu.w;
            }
            (sd ? ad_ : as_)[n * 4 + head] = a;
        }
    }
}

// One wave per dst node; two edges/iter; lane owns 8 channels (uint4 of bf16).
__global__ __launch_bounds__(256) void k_gat(
        const __hip_bfloat16* __restrict__ xh, const float* __restrict__ as_,
        const float* __restrict__ ad_, const int* __restrict__ rowptr,
        const int* __restrict__ csr, const float* __restrict__ convb,
        const float* __restrict__ ln_g, const float* __restrict__ ln_b,
        float* __restrict__ h, int N) {
    int wid = threadIdx.x >> 6, lane = threadIdx.x & 63;
    int n = blockIdx.x * 4 + wid;
    if (n >= N) return;
    int half = lane >> 5;
    int l32  = lane & 31;
    int head = l32 >> 3;
    int r0 = rowptr[n], r1 = rowptr[n + 1];
    float adv = ad_[(size_t)n * 4 + head];

    float s = 0.f;
    float a0 = 0.f, a1 = 0.f, a2 = 0.f, a3 = 0.f;
    float a4 = 0.f, a5 = 0.f, a6 = 0.f, a7 = 0.f;

    int idx = r0 + half;
    bool v = idx < r1;
    int src = csr[v ? idx : (r1 - 1)];
    float asv = as_[(size_t)src * 4 + head];
    uint4 p = *(const uint4*)(xh + (size_t)src * 256 + l32 * 8);

    for (int i = r0; i < r1; i += 2) {
        bool vc = v; float asc = asv; uint4 pc = p;
        int idxN = i + 2 + half;
        v = idxN < r1;
        if (v) {
            src = csr[idxN];
            asv = as_[(size_t)src * 4 + head];
            p = *(const uint4*)(xh + (size_t)src * 256 + l32 * 8);
        }
        float e = asc + adv;
        e = e > 0.f ? e : NEG_SLOPE * e;
        float w = __expf(e);
        w = vc ? w : 0.f;
        s += w;
        a0 = fmaf(w, __uint_as_float(pc.x << 16),          a0);
        a1 = fmaf(w, __uint_as_float(pc.x & 0xffff0000u),  a1);
        a2 = fmaf(w, __uint_as_float(pc.y << 16),          a2);
        a3 = fmaf(w, __uint_as_float(pc.y & 0xffff0000u),  a3);
        a4 = fmaf(w, __uint_as_float(pc.z << 16),          a4);
        a5 = fmaf(w, __uint_as_float(pc.z & 0xffff0000u),  a5);
        a6 = fmaf(w, __uint_as_float(pc.w << 16),          a6);
        a7 = fmaf(w, __uint_as_float(pc.w & 0xffff0000u),  a7);
    }

    s  += __shfl_xor(s, 32, 64);
    a0 += __shfl_xor(a0, 32, 64); a1 += __shfl_xor(a1, 32, 64);
    a2 += __shfl_xor(a2, 32, 64); a3 += __shfl_xor(a3, 32, 64);
    a4 += __shfl_xor(a4, 32, 64); a5 += __shfl_xor(a5, 32, 64);
    a6 += __shfl_xor(a6, 32, 64); a7 += __shfl_xor(a7, 32, 64);
    float inv = 1.f / (s + 1e-16f);
    a0 *= inv; a1 *= inv; a2 *= inv; a3 *= inv;
    a4 *= inv; a5 *= inv; a6 *= inv; a7 *= inv;
#pragma unroll
    for (int off = 8; off <= 16; off <<= 1) {
        a0 += __shfl_xor(a0, off, 64); a1 += __shfl_xor(a1, off, 64);
        a2 += __shfl_xor(a2, off, 64); a3 += __shfl_xor(a3, off, 64);
        a4 += __shfl_xor(a4, off, 64); a5 += __shfl_xor(a5, off, 64);
        a6 += __shfl_xor(a6, off, 64); a7 += __shfl_xor(a7, off, 64);
    }
    int cbase = (l32 & 7) * 8;
    float4 cbA = *(const float4*)(convb + cbase);
    float4 cbB = *(const float4*)(convb + cbase + 4);
    float o0 = 0.25f * a0 + cbA.x, o1 = 0.25f * a1 + cbA.y;
    float o2 = 0.25f * a2 + cbA.z, o3 = 0.25f * a3 + cbA.w;
    float o4 = 0.25f * a4 + cbB.x, o5 = 0.25f * a5 + cbB.y;
    float o6 = 0.25f * a6 + cbB.z, o7 = 0.25f * a7 + cbB.w;
    float part = o0 + o1 + o2 + o3 + o4 + o5 + o6 + o7;
#pragma unroll
    for (int off = 1; off <= 4; off <<= 1) part += __shfl_xor(part, off, 64);
    float mu = part * (1.f / 64.f);
    float d0 = o0 - mu, d1 = o1 - mu, d2 = o2 - mu, d3 = o3 - mu;
    float d4 = o4 - mu, d5 = o5 - mu, d6 = o6 - mu, d7 = o7 - mu;
    float vs = d0*d0 + d1*d1 + d2*d2 + d3*d3 + d4*d4 + d5*d5 + d6*d6 + d7*d7;
#pragma unroll
    for (int off = 1; off <= 4; off <<= 1) vs += __shfl_xor(vs, off, 64);
    float rstd = rsqrtf(vs * (1.f / 64.f) + LN_EPS);
    float4 gA = *(const float4*)(ln_g + cbase);
    float4 gB = *(const float4*)(ln_g + cbase + 4);
    float4 bA = *(const float4*)(ln_b + cbase);
    float4 bB = *(const float4*)(ln_b + cbase + 4);
    if (lane < 8) {
        float4* hp = (float4*)(h + (size_t)n * 64 + cbase);
        float4 hA = hp[0], hB = hp[1];
        hA.x += fmaxf(d0 * rstd * gA.x + bA.x, 0.f);
        hA.y += fmaxf(d1 * rstd * gA.y + bA.y, 0.f);
        hA.z += fmaxf(d2 * rstd * gA.z + bA.z, 0.f);
        hA.w += fmaxf(d3 * rstd * gA.w + bA.w, 0.f);
        hB.x += fmaxf(d4 * rstd * gB.x + bB.x, 0.f);
        hB.y += fmaxf(d5 * rstd * gB.y + bB.y, 0.f);
        hB.z += fmaxf(d6 * rstd * gB.z + bB.z, 0.f);
        hB.w += fmaxf(d7 * rstd * gB.w + bB.w, 0.f);
        hp[0] = hA; hp[1] = hB;
    }
}

// out = h @ out_W.T + out_b, vectorized
__global__ __launch_bounds__(256) void k_out(
        const float* __restrict__ h, const float* __restrict__ out_W,
        const float* __restrict__ out_b, float* __restrict__ out, int N) {
    __shared__ float hs[8][64];
    int t = threadIdx.x;
    int n0 = blockIdx.x * 8;
    for (int i = t; i < 512; i += 256) {
        int n = n0 + (i >> 6);
        hs[i >> 6][i & 63] = (n < N) ? h[(size_t)n * 64 + (i & 63)] : 0.f;
    }
    __syncthreads();
    int j = t >> 5, o = t & 31;
    int n = n0 + j;
    if (n >= N) return;
    float acc = out_b[o];
    const float4* w4 = (const float4*)(out_W + o * 64);
    const float4* h4 = (const float4*)&hs[j][0];
#pragma unroll
    for (int k = 0; k < 16; ++k) {
        float4 wv = w4[k], hv = h4[k];
        acc += hv.x * wv.x + hv.y * wv.y + hv.z * wv.z + hv.w * wv.w;
    }
    out[(size_t)n * 32 + o] = acc;
}

static inline unsigned cdiv(long long a, long long b) { return (unsigned)((a + b - 1) / b); }

extern "C" void kernel_launch(void* const* d_in, const int* in_sizes, int n_in,
                              void* d_out, int out_size, void* d_ws, size_t ws_size,
                              hipStream_t stream) {
    const float* x          = (const float*)d_in[0];
    const float* drone_feat = (const float*)d_in[1];
    const int*   edge_index = (const int*)d_in[2];
    const int*   batch      = (const int*)d_in[3];
    const float* node_W     = (const float*)d_in[4];
    const float* node_b     = (const float*)d_in[5];
    const float* drone_W    = (const float*)d_in[6];
    const float* drone_b    = (const float*)d_in[7];
    const float* convW[2]   = {(const float*)d_in[8],  (const float*)d_in[14]};
    const float* att_src[2] = {(const float*)d_in[9],  (const float*)d_in[15]};
    const float* att_dst[2] = {(const float*)d_in[10], (const float*)d_in[16]};
    const float* convb[2]   = {(const float*)d_in[11], (const float*)d_in[17]};
    const float* ln_g[2]    = {(const float*)d_in[12], (const float*)d_in[18]};
    const float* ln_b[2]    = {(const float*)d_in[13], (const float*)d_in[19]};
    const float* out_W      = (const float*)d_in[20];
    const float* out_b      = (const float*)d_in[21];
    float* out = (float*)d_out;

    const int N = in_sizes[0] / 32;
    const int E = in_sizes[2] / 2;
    const int Etot = E + N;
    const int NB = cdiv(N, 1024);

    char* base = (char*)d_ws;
    size_t off = 0;
    auto alloc = [&](size_t bytes) {
        char* p = base + off;
        off = (off + bytes + 255) & ~(size_t)255;
        return p;
    };
    float*           h      = (float*)alloc((size_t)N * 64 * 4);
    __hip_bfloat16*  xh     = (__hip_bfloat16*)alloc((size_t)N * 256 * 2);
    float*           as_    = (float*)alloc((size_t)N * 4 * 4);
    float*           ad_    = (float*)alloc((size_t)N * 4 * 4);
    float*           wt0    = (float*)alloc((size_t)256 * 64 * 4);
    float*           wt1    = (float*)alloc((size_t)256 * 64 * 4);
    float*           uv     = (float*)alloc((size_t)1024 * 4);
    float*           wnT    = (float*)alloc((size_t)2048 * 4);
    float*           wdT    = (float*)alloc((size_t)1024 * 4);
    float*           bias   = (float*)alloc((size_t)64 * 4);
    int*             deg    = (int*)alloc((size_t)N * 4);
    int*             rowptr = (int*)alloc((size_t)(N + 1) * 4);
    int*             cursor = (int*)alloc((size_t)N * 4);
    int*             csr    = (int*)alloc((size_t)Etot * 4);
    int*             bsum   = (int*)alloc((size_t)256 * 4);
    (void)ws_size;
    const float* wt[2] = {wt0, wt1};

    k_prep<<<128, 256, 0, stream>>>(convW[0], convW[1], att_src[0], att_dst[0],
                                    att_src[1], att_dst[1], node_W, drone_W,
                                    node_b, drone_b, wt0, wt1, uv, wnT, wdT, bias);

    k_h0<<<cdiv(N, 16), 256, 0, stream>>>(x, batch, wnT, wdT, bias, drone_feat, h, N);

    (void)hipMemsetAsync(deg, 0, (size_t)N * 4, stream);
    k_count<<<cdiv(E, 256), 256, 0, stream>>>(edge_index, deg, E);
    k_bsum<<<NB, 256, 0, stream>>>(deg, bsum, N);
    k_fill<<<NB, 256, 0, stream>>>(deg, bsum, rowptr, cursor, csr, N, Etot, NB);
    k_scatter<<<cdiv(E, 256), 256, 0, stream>>>(edge_index, cursor, csr, E);

    for (int l = 0; l < 2; ++l) {
        k_xh<<<cdiv(N, 32), 256, 0, stream>>>(h, wt[l], uv + l * 512, xh, as_, ad_, N);
        k_gat<<<cdiv(N, 4), 256, 0, stream>>>(xh, as_, ad_, rowptr, csr, convb[l],
                                              ln_g[l], ln_b[l], h, N);
    }

    k_out<<<cdiv(N, 8), 256, 0, stream>>>(h, out_W, out_b, out, N);
}

// Round 16
// 819.507 us; speedup vs baseline: 1.6099x; 1.0580x over previous
//
#include <hip/hip_runtime.h>
#include <hip/hip_bf16.h>
#include <math.h>

// N=100000, E=1600000, G=64, H=4, C=64, NODE_F=32, DRONE_F=16, OUT=32, L=2

#define NEG_SLOPE 0.2f
#define LN_EPS 1e-5f

struct __align__(8) bf16x4 { __hip_bfloat16 x, y, z, w; };

// h = x@node_W.T + drone_feat[batch]@drone_W.T + (node_b+drone_b)
__global__ __launch_bounds__(256) void k_h0(
        const float* __restrict__ x, const int* __restrict__ batch,
        const float* __restrict__ wnT, const float* __restrict__ wdT,
        const float* __restrict__ bias, const float* __restrict__ drone_feat,
        float* __restrict__ h, int N) {
    __shared__ float xs[16][33];
    __shared__ float ds[16][17];
    int t = threadIdx.x;
    int n0 = blockIdx.x * 16;
    for (int i = t; i < 512; i += 256) {
        int r = i >> 5, c = i & 31;
        int n = n0 + r;
        xs[r][c] = (n < N) ? x[(size_t)n * 32 + c] : 0.f;
    }
    {
        int r = t >> 4, c = t & 15;
        int n = n0 + r;
        int g = (n < N) ? batch[n] : 0;
        ds[r][c] = drone_feat[g * 16 + c];
    }
    __syncthreads();
    int co = t & 63;
    int nsub = t >> 6;
    float b = bias[co];
    float a0 = b, a1 = b, a2 = b, a3 = b;
#pragma unroll
    for (int k = 0; k < 32; ++k) {
        float w = wnT[k * 64 + co];
        a0 = fmaf(xs[nsub * 4 + 0][k], w, a0);
        a1 = fmaf(xs[nsub * 4 + 1][k], w, a1);
        a2 = fmaf(xs[nsub * 4 + 2][k], w, a2);
        a3 = fmaf(xs[nsub * 4 + 3][k], w, a3);
    }
#pragma unroll
    for (int k = 0; k < 16; ++k) {
        float w = wdT[k * 64 + co];
        a0 = fmaf(ds[nsub * 4 + 0][k], w, a0);
        a1 = fmaf(ds[nsub * 4 + 1][k], w, a1);
        a2 = fmaf(ds[nsub * 4 + 2][k], w, a2);
        a3 = fmaf(ds[nsub * 4 + 3][k], w, a3);
    }
    float av[4] = {a0, a1, a2, a3};
#pragma unroll
    for (int j = 0; j < 4; ++j) {
        int n = n0 + nsub * 4 + j;
        if (n < N) h[(size_t)n * 64 + co] = av[j];
    }
}

// degree histogram, 1 edge/thread (max parallelism, distributed atomics)
__global__ void k_count(const int* __restrict__ edge_index, int* __restrict__ deg, int E) {
    int i = blockIdx.x * blockDim.x + threadIdx.x;
    if (i < E) atomicAdd(deg + edge_index[E + i], 1);
}

// per-1024-chunk sums of (deg+1)
__global__ __launch_bounds__(256) void k_bsum(const int* __restrict__ deg,
                                              int* __restrict__ bsum, int N) {
    int t = threadIdx.x;
    int base = blockIdx.x * 1024 + t * 4;
    int s = 0;
#pragma unroll
    for (int j = 0; j < 4; ++j) s += (base + j < N) ? (deg[base + j] + 1) : 0;
    int lane = t & 63, wid = t >> 6;
#pragma unroll
    for (int off = 32; off >= 1; off >>= 1) s += __shfl_xor(s, off, 64);
    __shared__ int ws[4];
    if (lane == 0) ws[wid] = s;
    __syncthreads();
    if (t == 0) bsum[blockIdx.x] = ws[0] + ws[1] + ws[2] + ws[3];
}

// fill rowptr/cursor; self-loop written into csr[rowptr[n]] (dense writes);
// cursor starts at rowptr+1.
__global__ __launch_bounds__(256) void k_fill(const int* __restrict__ deg,
                                              const int* __restrict__ bsum,
                                              int* __restrict__ rowptr,
                                              int* __restrict__ cursor,
                                              int* __restrict__ csr,
                                              int N, int Etot, int NB) {
    __shared__ int sc[256];
    __shared__ int wsum2[4];
    int t = threadIdx.x;
    int lane = t & 63, wid = t >> 6;
    int bs = (t < NB) ? bsum[t] : 0;
    int v2 = bs;
#pragma unroll
    for (int off = 1; off < 64; off <<= 1) {
        int u = __shfl_up(v2, off, 64);
        if (lane >= off) v2 += u;
    }
    if (lane == 63) wsum2[wid] = v2;
    __syncthreads();
    int woff2 = 0;
    for (int w = 0; w < wid; ++w) woff2 += wsum2[w];
    sc[t] = woff2 + v2 - bs;
    __syncthreads();
    int blkoff = sc[blockIdx.x];

    int base = blockIdx.x * 1024 + t * 4;
    int d[4];
#pragma unroll
    for (int j = 0; j < 4; ++j) d[j] = (base + j < N) ? (deg[base + j] + 1) : 0;
    int s = d[0] + d[1] + d[2] + d[3];
    int v = s;
#pragma unroll
    for (int off = 1; off < 64; off <<= 1) {
        int u = __shfl_up(v, off, 64);
        if (lane >= off) v += u;
    }
    __shared__ int wsum[4];
    if (lane == 63) wsum[wid] = v;
    __syncthreads();
    int woff = 0;
    for (int w = 0; w < wid; ++w) woff += wsum[w];
    int off0 = blkoff + woff + v - s;
#pragma unroll
    for (int j = 0; j < 4; ++j) {
        int idx = base + j;
        if (idx < N) {
            rowptr[idx] = off0;
            csr[off0] = idx;          // self loop occupies the first slot
            cursor[idx] = off0 + 1;
        }
        off0 += d[j];
    }
    if (blockIdx.x == 0 && t == 0) rowptr[N] = Etot;
}

// scatter real edges in P dst-range passes (blockIdx.y = pass).
// Distributed atomics (100K cursors) + per-pass dense csr window (~860 KB,
// L2-resident, ~1x write-allocate amplification). Streaming int4 re-reads.
__global__ void k_scatter(const int* __restrict__ edge_index, int* __restrict__ cursor,
                          int* __restrict__ csr, int E, int S) {
    int lo = blockIdx.y * S, hi = lo + S;
    int i = (blockIdx.x * blockDim.x + threadIdx.x) * 4;
    if (i + 3 < E) {
        int4 sv = *(const int4*)(edge_index + i);
        int4 dv = *(const int4*)(edge_index + E + i);
        if (dv.x >= lo && dv.x < hi) csr[atomicAdd(cursor + dv.x, 1)] = sv.x;
        if (dv.y >= lo && dv.y < hi) csr[atomicAdd(cursor + dv.y, 1)] = sv.y;
        if (dv.z >= lo && dv.z < hi) csr[atomicAdd(cursor + dv.z, 1)] = sv.z;
        if (dv.w >= lo && dv.w < hi) csr[atomicAdd(cursor + dv.w, 1)] = sv.w;
    } else {
        for (int k = i; k < E; ++k) {
            int d = edge_index[E + k];
            if (d >= lo && d < hi) csr[atomicAdd(cursor + d, 1)] = edge_index[k];
        }
    }
}

// weight transposes + uv + bias, one dispatch
__global__ void k_prep(const float* __restrict__ cW0, const float* __restrict__ cW1,
                       const float* __restrict__ s0, const float* __restrict__ d0,
                       const float* __restrict__ s1, const float* __restrict__ d1,
                       const float* __restrict__ node_W, const float* __restrict__ drone_W,
                       const float* __restrict__ node_b, const float* __restrict__ drone_b,
                       float* __restrict__ wt0, float* __restrict__ wt1,
                       float* __restrict__ uv, float* __restrict__ wnT,
                       float* __restrict__ wdT, float* __restrict__ bias) {
    int i = blockIdx.x * blockDim.x + threadIdx.x;
    if (i < 32768) {
        int j = i & 16383;
        int co = j >> 6, k = j & 63;
        if (i < 16384) wt0[k * 256 + co] = cW0[j];
        else           wt1[k * 256 + co] = cW1[j];
    }
    if (i < 2048) {
        int k = i >> 6, co = i & 63;
        wnT[i] = node_W[co * 32 + k];
    }
    if (i < 1024) {
        int k = i >> 6, co = i & 63;
        wdT[i] = drone_W[co * 16 + k];
        int l = i >> 9, sd = (i >> 8) & 1, head = (i >> 6) & 3, kk = i & 63;
        const float* W   = l ? cW1 : cW0;
        const float* att = l ? (sd ? d1 : s1) : (sd ? d0 : s0);
        float acc = 0.f;
        for (int c = 0; c < 64; ++c)
            acc += W[(head * 64 + c) * 64 + kk] * att[head * 64 + c];
        uv[i] = acc;
    }
    if (i < 64) bias[i] = node_b[i] + drone_b[i];
}

// xh[n][256] = h[n] @ convW.T (bf16) + fused as_/ad_. TN=32 nodes/block.
#define XPAD 68
__global__ __launch_bounds__(256) void k_xh(
        const float* __restrict__ h, const float* __restrict__ wt,
        const float* __restrict__ uv_l, __hip_bfloat16* __restrict__ xh,
        float* __restrict__ as_, float* __restrict__ ad_, int N) {
    __shared__ float hs[32][XPAD];
    int t = threadIdx.x;
    int n0 = blockIdx.x * 32;
    for (int i = t; i < 32 * 64; i += 256) {
        int r = i >> 6, c = i & 63;
        int n = n0 + r;
        hs[r][c] = (n < N) ? h[(size_t)n * 64 + c] : 0.f;
    }
    __syncthreads();
    int co4 = (t & 63) * 4;
    int nsub = t >> 6;
    float4 acc[8];
#pragma unroll
    for (int j = 0; j < 8; ++j) acc[j] = make_float4(0.f, 0.f, 0.f, 0.f);
    const float* wp = wt + co4;
#pragma unroll 2
    for (int k4 = 0; k4 < 16; ++k4) {
        float4 w0 = *(const float4*)(wp + (k4 * 4 + 0) * 256);
        float4 w1 = *(const float4*)(wp + (k4 * 4 + 1) * 256);
        float4 w2 = *(const float4*)(wp + (k4 * 4 + 2) * 256);
        float4 w3 = *(const float4*)(wp + (k4 * 4 + 3) * 256);
#pragma unroll
        for (int j = 0; j < 8; ++j) {
            float4 hv = *(const float4*)&hs[nsub * 8 + j][k4 * 4];
            float4 a = acc[j];
            a.x = fmaf(hv.x, w0.x, fmaf(hv.y, w1.x, fmaf(hv.z, w2.x, fmaf(hv.w, w3.x, a.x))));
            a.y = fmaf(hv.x, w0.y, fmaf(hv.y, w1.y, fmaf(hv.z, w2.y, fmaf(hv.w, w3.y, a.y))));
            a.z = fmaf(hv.x, w0.z, fmaf(hv.y, w1.z, fmaf(hv.z, w2.z, fmaf(hv.w, w3.z, a.z))));
            a.w = fmaf(hv.x, w0.w, fmaf(hv.y, w1.w, fmaf(hv.z, w2.w, fmaf(hv.w, w3.w, a.w))));
            acc[j] = a;
        }
    }
#pragma unroll
    for (int j = 0; j < 8; ++j) {
        int n = n0 + nsub * 8 + j;
        if (n < N) {
            bf16x4 o;
            o.x = __float2bfloat16(acc[j].x);
            o.y = __float2bfloat16(acc[j].y);
            o.z = __float2bfloat16(acc[j].z);
            o.w = __float2bfloat16(acc[j].w);
            *(bf16x4*)(xh + (size_t)n * 256 + co4) = o;
        }
    }
    {
        int row  = t >> 3;
        int head = (t >> 1) & 3;
        int sd   = t & 1;
        int n = n0 + row;
        if (n < N) {
            const float* u = uv_l + sd * 256 + head * 64;
            float a = 0.f;
#pragma unroll
            for (int k4 = 0; k4 < 16; ++k4) {
                float4 hv = *(const float4*)&hs[row][k4 * 4];
                float4 uu = *(const float4*)(u + k4 * 4);
                a += hv.x * uu.x + hv.y * uu.y + hv.z * uu.z + hv.w * uu.w;
            }
            (sd ? ad_ : as_)[n * 4 + head] = a;
        }
    }
}

// One wave per dst node; two edges/iter; lane owns 8 channels (uint4 of bf16).
__global__ __launch_bounds__(256) void k_gat(
        const __hip_bfloat16* __restrict__ xh, const float* __restrict__ as_,
        const float* __restrict__ ad_, const int* __restrict__ rowptr,
        const int* __restrict__ csr, const float* __restrict__ convb,
        const float* __restrict__ ln_g, const float* __restrict__ ln_b,
        float* __restrict__ h, int N) {
    int wid = threadIdx.x >> 6, lane = threadIdx.x & 63;
    int n = blockIdx.x * 4 + wid;
    if (n >= N) return;
    int half = lane >> 5;
    int l32  = lane & 31;
    int head = l32 >> 3;
    int r0 = rowptr[n], r1 = rowptr[n + 1];
    float adv = ad_[(size_t)n * 4 + head];

    float s = 0.f;
    float a0 = 0.f, a1 = 0.f, a2 = 0.f, a3 = 0.f;
    float a4 = 0.f, a5 = 0.f, a6 = 0.f, a7 = 0.f;

    int idx = r0 + half;
    bool v = idx < r1;
    int src = csr[v ? idx : (r1 - 1)];
    float asv = as_[(size_t)src * 4 + head];
    uint4 p = *(const uint4*)(xh + (size_t)src * 256 + l32 * 8);

    for (int i = r0; i < r1; i += 2) {
        bool vc = v; float asc = asv; uint4 pc = p;
        int idxN = i + 2 + half;
        v = idxN < r1;
        if (v) {
            src = csr[idxN];
            asv = as_[(size_t)src * 4 + head];
            p = *(const uint4*)(xh + (size_t)src * 256 + l32 * 8);
        }
        float e = asc + adv;
        e = e > 0.f ? e : NEG_SLOPE * e;
        float w = __expf(e);
        w = vc ? w : 0.f;
        s += w;
        a0 = fmaf(w, __uint_as_float(pc.x << 16),          a0);
        a1 = fmaf(w, __uint_as_float(pc.x & 0xffff0000u),  a1);
        a2 = fmaf(w, __uint_as_float(pc.y << 16),          a2);
        a3 = fmaf(w, __uint_as_float(pc.y & 0xffff0000u),  a3);
        a4 = fmaf(w, __uint_as_float(pc.z << 16),          a4);
        a5 = fmaf(w, __uint_as_float(pc.z & 0xffff0000u),  a5);
        a6 = fmaf(w, __uint_as_float(pc.w << 16),          a6);
        a7 = fmaf(w, __uint_as_float(pc.w & 0xffff0000u),  a7);
    }

    s  += __shfl_xor(s, 32, 64);
    a0 += __shfl_xor(a0, 32, 64); a1 += __shfl_xor(a1, 32, 64);
    a2 += __shfl_xor(a2, 32, 64); a3 += __shfl_xor(a3, 32, 64);
    a4 += __shfl_xor(a4, 32, 64); a5 += __shfl_xor(a5, 32, 64);
    a6 += __shfl_xor(a6, 32, 64); a7 += __shfl_xor(a7, 32, 64);
    float inv = 1.f / (s + 1e-16f);
    a0 *= inv; a1 *= inv; a2 *= inv; a3 *= inv;
    a4 *= inv; a5 *= inv; a6 *= inv; a7 *= inv;
#pragma unroll
    for (int off = 8; off <= 16; off <<= 1) {
        a0 += __shfl_xor(a0, off, 64); a1 += __shfl_xor(a1, off, 64);
        a2 += __shfl_xor(a2, off, 64); a3 += __shfl_xor(a3, off, 64);
        a4 += __shfl_xor(a4, off, 64); a5 += __shfl_xor(a5, off, 64);
        a6 += __shfl_xor(a6, off, 64); a7 += __shfl_xor(a7, off, 64);
    }
    int cbase = (l32 & 7) * 8;
    float4 cbA = *(const float4*)(convb + cbase);
    float4 cbB = *(const float4*)(convb + cbase + 4);
    float o0 = 0.25f * a0 + cbA.x, o1 = 0.25f * a1 + cbA.y;
    float o2 = 0.25f * a2 + cbA.z, o3 = 0.25f * a3 + cbA.w;
    float o4 = 0.25f * a4 + cbB.x, o5 = 0.25f * a5 + cbB.y;
    float o6 = 0.25f * a6 + cbB.z, o7 = 0.25f * a7 + cbB.w;
    float part = o0 + o1 + o2 + o3 + o4 + o5 + o6 + o7;
#pragma unroll
    for (int off = 1; off <= 4; off <<= 1) part += __shfl_xor(part, off, 64);
    float mu = part * (1.f / 64.f);
    float d0 = o0 - mu, d1 = o1 - mu, d2 = o2 - mu, d3 = o3 - mu;
    float d4 = o4 - mu, d5 = o5 - mu, d6 = o6 - mu, d7 = o7 - mu;
    float vs = d0*d0 + d1*d1 + d2*d2 + d3*d3 + d4*d4 + d5*d5 + d6*d6 + d7*d7;
#pragma unroll
    for (int off = 1; off <= 4; off <<= 1) vs += __shfl_xor(vs, off, 64);
    float rstd = rsqrtf(vs * (1.f / 64.f) + LN_EPS);
    float4 gA = *(const float4*)(ln_g + cbase);
    float4 gB = *(const float4*)(ln_g + cbase + 4);
    float4 bA = *(const float4*)(ln_b + cbase);
    float4 bB = *(const float4*)(ln_b + cbase + 4);
    if (lane < 8) {
        float4* hp = (float4*)(h + (size_t)n * 64 + cbase);
        float4 hA = hp[0], hB = hp[1];
        hA.x += fmaxf(d0 * rstd * gA.x + bA.x, 0.f);
        hA.y += fmaxf(d1 * rstd * gA.y + bA.y, 0.f);
        hA.z += fmaxf(d2 * rstd * gA.z + bA.z, 0.f);
        hA.w += fmaxf(d3 * rstd * gA.w + bA.w, 0.f);
        hB.x += fmaxf(d4 * rstd * gB.x + bB.x, 0.f);
        hB.y += fmaxf(d5 * rstd * gB.y + bB.y, 0.f);
        hB.z += fmaxf(d6 * rstd * gB.z + bB.z, 0.f);
        hB.w += fmaxf(d7 * rstd * gB.w + bB.w, 0.f);
        hp[0] = hA; hp[1] = hB;
    }
}

// out = h @ out_W.T + out_b, vectorized
__global__ __launch_bounds__(256) void k_out(
        const float* __restrict__ h, const float* __restrict__ out_W,
        const float* __restrict__ out_b, float* __restrict__ out, int N) {
    __shared__ float hs[8][64];
    int t = threadIdx.x;
    int n0 = blockIdx.x * 8;
    for (int i = t; i < 512; i += 256) {
        int n = n0 + (i >> 6);
        hs[i >> 6][i & 63] = (n < N) ? h[(size_t)n * 64 + (i & 63)] : 0.f;
    }
    __syncthreads();
    int j = t >> 5, o = t & 31;
    int n = n0 + j;
    if (n >= N) return;
    float acc = out_b[o];
    const float4* w4 = (const float4*)(out_W + o * 64);
    const float4* h4 = (const float4*)&hs[j][0];
#pragma unroll
    for (int k = 0; k < 16; ++k) {
        float4 wv = w4[k], hv = h4[k];
        acc += hv.x * wv.x + hv.y * wv.y + hv.z * wv.z + hv.w * wv.w;
    }
    out[(size_t)n * 32 + o] = acc;
}

static inline unsigned cdiv(long long a, long long b) { return (unsigned)((a + b - 1) / b); }

extern "C" void kernel_launch(void* const* d_in, const int* in_sizes, int n_in,
                              void* d_out, int out_size, void* d_ws, size_t ws_size,
                              hipStream_t stream) {
    const float* x          = (const float*)d_in[0];
    const float* drone_feat = (const float*)d_in[1];
    const int*   edge_index = (const int*)d_in[2];
    const int*   batch      = (const int*)d_in[3];
    const float* node_W     = (const float*)d_in[4];
    const float* node_b     = (const float*)d_in[5];
    const float* drone_W    = (const float*)d_in[6];
    const float* drone_b    = (const float*)d_in[7];
    const float* convW[2]   = {(const float*)d_in[8],  (const float*)d_in[14]};
    const float* att_src[2] = {(const float*)d_in[9],  (const float*)d_in[15]};
    const float* att_dst[2] = {(const float*)d_in[10], (const float*)d_in[16]};
    const float* convb[2]   = {(const float*)d_in[11], (const float*)d_in[17]};
    const float* ln_g[2]    = {(const float*)d_in[12], (const float*)d_in[18]};
    const float* ln_b[2]    = {(const float*)d_in[13], (const float*)d_in[19]};
    const float* out_W      = (const float*)d_in[20];
    const float* out_b      = (const float*)d_in[21];
    float* out = (float*)d_out;

    const int N = in_sizes[0] / 32;
    const int E = in_sizes[2] / 2;
    const int Etot = E + N;
    const int NB = cdiv(N, 1024);
    const int P = 8;                   // scatter passes
    const int S = cdiv(N, P);          // dst range per pass

    char* base = (char*)d_ws;
    size_t off = 0;
    auto alloc = [&](size_t bytes) {
        char* p = base + off;
        off = (off + bytes + 255) & ~(size_t)255;
        return p;
    };
    float*           h      = (float*)alloc((size_t)N * 64 * 4);
    __hip_bfloat16*  xh     = (__hip_bfloat16*)alloc((size_t)N * 256 * 2);
    float*           as_    = (float*)alloc((size_t)N * 4 * 4);
    float*           ad_    = (float*)alloc((size_t)N * 4 * 4);
    float*           wt0    = (float*)alloc((size_t)256 * 64 * 4);
    float*           wt1    = (float*)alloc((size_t)256 * 64 * 4);
    float*           uv     = (float*)alloc((size_t)1024 * 4);
    float*           wnT    = (float*)alloc((size_t)2048 * 4);
    float*           wdT    = (float*)alloc((size_t)1024 * 4);
    float*           bias   = (float*)alloc((size_t)64 * 4);
    int*             deg    = (int*)alloc((size_t)N * 4);
    int*             rowptr = (int*)alloc((size_t)(N + 1) * 4);
    int*             cursor = (int*)alloc((size_t)N * 4);
    int*             csr    = (int*)alloc((size_t)Etot * 4);
    int*             bsum   = (int*)alloc((size_t)256 * 4);
    (void)ws_size;
    const float* wt[2] = {wt0, wt1};

    k_prep<<<128, 256, 0, stream>>>(convW[0], convW[1], att_src[0], att_dst[0],
                                    att_src[1], att_dst[1], node_W, drone_W,
                                    node_b, drone_b, wt0, wt1, uv, wnT, wdT, bias);

    k_h0<<<cdiv(N, 16), 256, 0, stream>>>(x, batch, wnT, wdT, bias, drone_feat, h, N);

    (void)hipMemsetAsync(deg, 0, (size_t)N * 4, stream);
    k_count<<<cdiv(E, 256), 256, 0, stream>>>(edge_index, deg, E);
    k_bsum<<<NB, 256, 0, stream>>>(deg, bsum, N);
    k_fill<<<NB, 256, 0, stream>>>(deg, bsum, rowptr, cursor, csr, N, Etot, NB);
    {
        dim3 g(cdiv(cdiv(E, 4), 256), P);
        k_scatter<<<g, 256, 0, stream>>>(edge_index, cursor, csr, E, S);
    }

    for (int l = 0; l < 2; ++l) {
        k_xh<<<cdiv(N, 32), 256, 0, stream>>>(h, wt[l], uv + l * 512, xh, as_, ad_, N);
        k_gat<<<cdiv(N, 4), 256, 0, stream>>>(xh, as_, ad_, rowptr, csr, convb[l],
                                              ln_g[l], ln_b[l], h, N);
    }

    k_out<<<cdiv(N, 8), 256, 0, stream>>>(h, out_W, out_b, out, N);
}